// Round 4
// baseline (164.897 us; speedup 1.0000x reference)
//
#include <hip/hip_runtime.h>

#define DF 256  // feature dim

// ---- 1. histogram ----
__global__ void cp_count(const int* __restrict__ cmap, int* __restrict__ counts, int n) {
    int i = blockIdx.x * blockDim.x + threadIdx.x;
    if (i < n) atomicAdd(&counts[cmap[i]], 1);
}

// ---- 2a. per-block exclusive scan ----
__global__ void cp_scanA(const int* __restrict__ counts, int* __restrict__ offsets,
                         int* __restrict__ blocksums, int C) {
    __shared__ int s[256];
    int tid = threadIdx.x;
    int i = blockIdx.x * 256 + tid;
    int v = (i < C) ? counts[i] : 0;
    s[tid] = v;
    __syncthreads();
    for (int off = 1; off < 256; off <<= 1) {
        int t = (tid >= off) ? s[tid - off] : 0;
        __syncthreads();
        s[tid] += t;
        __syncthreads();
    }
    if (i < C) offsets[i] = s[tid] - v;
    if (tid == 255) blocksums[blockIdx.x] = s[255];
}

// ---- 2b. scan block sums ----
__global__ void cp_scanB(int* __restrict__ blocksums, int nb) {
    __shared__ int s[256];
    int tid = threadIdx.x;
    if (nb <= 256) {
        int v = (tid < nb) ? blocksums[tid] : 0;
        s[tid] = v;
        __syncthreads();
        for (int off = 1; off < 256; off <<= 1) {
            int t = (tid >= off) ? s[tid - off] : 0;
            __syncthreads();
            s[tid] += t;
            __syncthreads();
        }
        if (tid < nb) blocksums[tid] = s[tid] - v;
    } else if (tid == 0) {
        int run = 0;
        for (int k = 0; k < nb; ++k) { int t = blocksums[k]; blocksums[k] = run; run += t; }
    }
}

// ---- 2c. finalize offsets; build seg[c]={start,len}; init cursor=offsets ----
__global__ void cp_scanC(int* __restrict__ offsets, const int* __restrict__ blocksums,
                         const int* __restrict__ counts, int2* __restrict__ seg,
                         int* __restrict__ cursor, int C) {
    int i = blockIdx.x * 256 + threadIdx.x;
    if (i < C) {
        int st = offsets[i] + blocksums[blockIdx.x];
        offsets[i] = st;
        cursor[i] = st;
        seg[i] = make_int2(st, counts[i]);
    }
}

// ---- 3. bucket-fill: cursor pre-initialized to offsets -> one atomic, one store ----
__global__ void cp_fill(const int* __restrict__ cmap, int* __restrict__ cursor,
                        int* __restrict__ node_list, int n) {
    int i = blockIdx.x * blockDim.x + threadIdx.x;
    if (i < n) {
        int pos = atomicAdd(&cursor[cmap[i]], 1);
        node_list[pos] = i;
    }
}

// ---- 4. pool: persistent waves, pair-of-clusters + next-pair prologue prefetch ----
__global__ void __launch_bounds__(256) cp_pool(
        const float* __restrict__ x, const float* __restrict__ h,
        const int2* __restrict__ seg, const int* __restrict__ node_list,
        float* __restrict__ xp, float* __restrict__ hp, int C, int nwaves) {
    int gw   = (blockIdx.x * blockDim.x + threadIdx.x) >> 6;
    int lane = threadIdx.x & 63;
    int stride = 2 * nwaves;
    int cA = gw * 2;
    if (cA >= C) return;

    // prologue for first pair
    int2 sA = seg[cA];
    int2 sB = (cA + 1 < C) ? seg[cA + 1] : make_int2(0, 0);
    int nidA = (lane < sA.y) ? node_list[sA.x + lane] : 0;
    int nidB = (lane < sB.y) ? node_list[sB.x + lane] : 0;

    while (true) {
        // prefetch NEXT pair's prologue (hidden under this pair's row-load latency)
        int cN = cA + stride;
        int2 sA2 = make_int2(0, 0), sB2 = make_int2(0, 0);
        int nidA2 = 0, nidB2 = 0;
        if (cN < C) {
            sA2 = seg[cN];
            sB2 = (cN + 1 < C) ? seg[cN + 1] : make_int2(0, 0);
            nidA2 = (lane < sA2.y) ? node_list[sA2.x + lane] : 0;
            nidB2 = (lane < sB2.y) ? node_list[sB2.x + lane] : 0;
        }

        // interleaved accumulate of both clusters (lens are wave-uniform)
        float4 ax = make_float4(0.f, 0.f, 0.f, 0.f);
        float4 ah = make_float4(0.f, 0.f, 0.f, 0.f);
        float4 bx = make_float4(0.f, 0.f, 0.f, 0.f);
        float4 bh = make_float4(0.f, 0.f, 0.f, 0.f);
        int kA = sA.y < 64 ? sA.y : 64;
        int kB = sB.y < 64 ? sB.y : 64;
        int kmax = kA > kB ? kA : kB;
        for (int k = 0; k < kmax; ++k) {
            if (k < kA) {
                int n0 = __shfl(nidA, k);
                float4 xv = reinterpret_cast<const float4*>(x + (size_t)n0 * DF)[lane];
                float4 hv = reinterpret_cast<const float4*>(h + (size_t)n0 * DF)[lane];
                ax.x += xv.x; ax.y += xv.y; ax.z += xv.z; ax.w += xv.w;
                ah.x += hv.x; ah.y += hv.y; ah.z += hv.z; ah.w += hv.w;
            }
            if (k < kB) {
                int n1 = __shfl(nidB, k);
                float4 xv = reinterpret_cast<const float4*>(x + (size_t)n1 * DF)[lane];
                float4 hv = reinterpret_cast<const float4*>(h + (size_t)n1 * DF)[lane];
                bx.x += xv.x; bx.y += xv.y; bx.z += xv.z; bx.w += xv.w;
                bh.x += hv.x; bh.y += hv.y; bh.z += hv.z; bh.w += hv.w;
            }
        }
        // rare tails (len > 64)
        for (int kk = 64; kk < sA.y; ++kk) {
            int n0 = node_list[sA.x + kk];
            float4 xv = reinterpret_cast<const float4*>(x + (size_t)n0 * DF)[lane];
            float4 hv = reinterpret_cast<const float4*>(h + (size_t)n0 * DF)[lane];
            ax.x += xv.x; ax.y += xv.y; ax.z += xv.z; ax.w += xv.w;
            ah.x += hv.x; ah.y += hv.y; ah.z += hv.z; ah.w += hv.w;
        }
        for (int kk = 64; kk < sB.y; ++kk) {
            int n1 = node_list[sB.x + kk];
            float4 xv = reinterpret_cast<const float4*>(x + (size_t)n1 * DF)[lane];
            float4 hv = reinterpret_cast<const float4*>(h + (size_t)n1 * DF)[lane];
            bx.x += xv.x; bx.y += xv.y; bx.z += xv.z; bx.w += xv.w;
            bh.x += hv.x; bh.y += hv.y; bh.z += hv.z; bh.w += hv.w;
        }

        // store both clusters
        float invA = 1.0f / (float)(sA.y > 0 ? sA.y : 1);
        ax.x *= invA; ax.y *= invA; ax.z *= invA; ax.w *= invA;
        ah.x *= invA; ah.y *= invA; ah.z *= invA; ah.w *= invA;
        reinterpret_cast<float4*>(xp + (size_t)cA * DF)[lane] = ax;
        reinterpret_cast<float4*>(hp + (size_t)cA * DF)[lane] = ah;
        if (cA + 1 < C) {
            float invB = 1.0f / (float)(sB.y > 0 ? sB.y : 1);
            bx.x *= invB; bx.y *= invB; bx.z *= invB; bx.w *= invB;
            bh.x *= invB; bh.y *= invB; bh.z *= invB; bh.w *= invB;
            reinterpret_cast<float4*>(xp + (size_t)(cA + 1) * DF)[lane] = bx;
            reinterpret_cast<float4*>(hp + (size_t)(cA + 1) * DF)[lane] = bh;
        }

        if (cN >= C) break;
        cA = cN; sA = sA2; sB = sB2; nidA = nidA2; nidB = nidB2;
    }
}

// ---- 5. pos gather ----
__global__ void cp_pos(const float* __restrict__ pos, const int* __restrict__ sidx,
                       float* __restrict__ out, int C) {
    int i = blockIdx.x * blockDim.x + threadIdx.x;
    if (i >= C) return;
    int s = sidx[i];
    out[(size_t)i * 3 + 0] = pos[(size_t)s * 3 + 0];
    out[(size_t)i * 3 + 1] = pos[(size_t)s * 3 + 1];
    out[(size_t)i * 3 + 2] = pos[(size_t)s * 3 + 2];
}

extern "C" void kernel_launch(void* const* d_in, const int* in_sizes, int n_in,
                              void* d_out, int out_size, void* d_ws, size_t ws_size,
                              hipStream_t stream) {
    const float* x    = (const float*)d_in[0];
    const float* h    = (const float*)d_in[1];
    const float* pos  = (const float*)d_in[2];
    const int*   cmap = (const int*)d_in[3];
    const int*   sidx = (const int*)d_in[4];

    const int n_nodes = in_sizes[2] / 3;
    const int C       = in_sizes[4];

    float* out  = (float*)d_out;
    float* xp   = out;
    float* hp   = out + (size_t)C * DF;
    float* pout = out + (size_t)2 * C * DF;

    // ws ints: counts[C] | cursor[C] | offsets[C] | blocksums[256] | seg[2C] | node_list[N]
    int*  counts    = (int*)d_ws;
    int*  cursor    = counts + C;
    int*  offsets   = cursor + C;
    int*  blocksums = offsets + C;
    int2* seg       = (int2*)(blocksums + 256);
    int*  node_list = (int*)(seg + C);

    hipMemsetAsync(counts, 0, (size_t)C * sizeof(int), stream);

    cp_count<<<(n_nodes + 255) / 256, 256, 0, stream>>>(cmap, counts, n_nodes);

    int nb = (C + 255) / 256;
    cp_scanA<<<nb, 256, 0, stream>>>(counts, offsets, blocksums, C);
    cp_scanB<<<1, 256, 0, stream>>>(blocksums, nb);
    cp_scanC<<<nb, 256, 0, stream>>>(offsets, blocksums, counts, seg, cursor, C);

    cp_fill<<<(n_nodes + 255) / 256, 256, 0, stream>>>(cmap, cursor, node_list, n_nodes);

    // persistent grid: 2048 blocks x 4 waves = 8192 waves (max co-resident)
    int nblocks = 2048;
    int nwaves  = nblocks * 4;
    cp_pool<<<nblocks, 256, 0, stream>>>(x, h, seg, node_list, xp, hp, C, nwaves);

    cp_pos<<<(C + 255) / 256, 256, 0, stream>>>(pos, sidx, pout, C);
}